// Round 20
// baseline (187.226 us; speedup 1.0000x reference)
//
#include <hip/hip_runtime.h>
#include <stdint.h>

#define LSEQ 2048
#define M_TOT 32768          // B*L
#define KDIM 2048            // 2H
#define NKT 64               // K tiles of 32
#define NCT 4                // col tiles of 256
#define NEG_INF_F (-10000000000.0f)

typedef _Float16 f16;
typedef f16 f16x8 __attribute__((ext_vector_type(8)));
typedef float f32x4 __attribute__((ext_vector_type(4)));

// ---------------- ws layout ----------------
// [0, 64K)       sdec f32[16][1024]
// [64K, 576K)    part f32[4][32768]
// [576K, 704K)   pos  int[32768]
// [704K, 832K)   ridx int[32768]
// [832K, 833K)   nkeep int[16]  (nkeep[0] = global kept count)
// [2M, 6M)       weT  tiled fp16 B [4 ct][64 kt][1024 granules x 16B]
#define WS_SDEC_OFF  0
#define WS_PART_OFF  (64u << 10)
#define WS_POS_OFF   (576u << 10)
#define WS_RIDX_OFF  (704u << 10)
#define WS_NKEEP_OFF (832u << 10)
#define WS_WET_OFF   (2u << 20)

// LDS: A 2 slots x 8KB + B 3 slots x 16KB = 64KB  -> 2 blocks/CU
#define A_OFF(s) ((s) * 8192)
#define B_OFF(s) (16384 + (s) * 16384)

__device__ inline void gload16(const void* g, void* l) {
    __builtin_amdgcn_global_load_lds(
        (const __attribute__((address_space(1))) void*)g,
        (__attribute__((address_space(3))) void*)l, 16, 0, 0);
}

// fast tanh(x)*s with sign fold
__device__ inline float tanh_mul(float x, float s) {
    float ax = __builtin_fabsf(x);
    float e  = __expf(-2.f * ax);
    float th = (1.f - e) * __builtin_amdgcn_rcpf(1.f + e);
    float sv = __uint_as_float(__float_as_uint(s) ^ (__float_as_uint(x) & 0x80000000u));
    return th * sv;
}

// MERGED PREP: blocks [0,256) wecvt | [256,512) sdec (h-major) | 512 global compact.
__global__ __launch_bounds__(256) void prep_kernel(
        const float* __restrict__ attn_w, f16* __restrict__ weT,
        const float* __restrict__ v, const float* __restrict__ attn_b,
        float* __restrict__ sdec,
        const int* __restrict__ mask, int* __restrict__ ridx,
        int* __restrict__ pos, int* __restrict__ nkeep) {
    const int blk = blockIdx.x;
    const int tid = threadIdx.x;
    __shared__ int wsum[4];

    if (blk < 256) {
        // ---- wecvt: W_e -> tiled fp16 B, r5-verified 0-conflict swizzle ----
        int g = blk * 1024 + tid;
        #pragma unroll
        for (int q = 0; q < 4; ++q, g += 256) {
            int ct  = g >> 16;
            int rem = g & 65535;
            int kt  = rem >> 10;
            int p   = rem & 1023;
            int row = p >> 2;
            int sl  = (p & 3) ^ ((row >> 1) & 3);
            const float* s = attn_w + (size_t)(ct * 256 + row) * 3072 + 1024 + kt * 32 + sl * 8;
            float4 a = *(const float4*)s;
            float4 b = *(const float4*)(s + 4);
            f16x8 h = { (f16)a.x,(f16)a.y,(f16)a.z,(f16)a.w,(f16)b.x,(f16)b.y,(f16)b.z,(f16)b.w };
            *(f16x8*)(weT + (size_t)g * 8) = h;
        }
    } else if (blk < 512) {
        // ---- sdec, h-major: one wave per h, loop 16 batches (W_v read once) ----
        const int h = (blk - 256) * 4 + (tid >> 6);
        const int lane = tid & 63;
        const float* wr = attn_w + (size_t)h * 3072;
        float s[16];
        #pragma unroll
        for (int b = 0; b < 16; ++b) s[b] = 0.f;
        for (int k = 0; k < 16; ++k) {
            const int idx = lane + 64 * k;
            const float w_ = wr[idx];
            #pragma unroll
            for (int b = 0; b < 16; ++b) s[b] += v[b * 1024 + idx] * w_;
        }
        const float bias = attn_b[h];
        #pragma unroll
        for (int b = 0; b < 16; ++b) {
            float t = s[b];
            #pragma unroll
            for (int m = 1; m < 64; m <<= 1) t += __shfl_xor(t, m);
            if (lane == 0) sdec[b * 1024 + h] = t + bias;
        }
    } else {
        // ---- GLOBAL compact: 256 threads x 128 rows, one block ----
        const int lane = tid & 63, w = tid >> 6;
        const int base = tid * 128;
        int cnt = 0;
        for (int i = 0; i < 128; ++i) cnt += (mask[base + i] != 0);
        int inc = cnt;
        #pragma unroll
        for (int d = 1; d < 64; d <<= 1) {
            int t = __shfl_up(inc, d);
            if (lane >= d) inc += t;
        }
        if (lane == 63) wsum[w] = inc;
        __syncthreads();
        int wbase = 0, total = 0;
        #pragma unroll
        for (int i = 0; i < 4; ++i) { if (i < w) wbase += wsum[i]; total += wsum[i]; }
        int p = wbase + inc - cnt;   // exclusive prefix
        for (int i = 0; i < 128; ++i) {
            const int r = base + i;
            if (mask[r] != 0) { ridx[p] = r; pos[r] = p; p++; }
            else              { pos[r] = -1; }
        }
        if (tid == 0) nkeep[0] = total;
    }
}

#define PH_OPEN  do { __builtin_amdgcn_sched_barrier(0); __builtin_amdgcn_s_barrier(); \
                      asm volatile("s_waitcnt lgkmcnt(0)" ::: "memory"); \
                      __builtin_amdgcn_sched_barrier(0); } while (0)
#define PH_CLOSE do { __builtin_amdgcn_sched_barrier(0); __builtin_amdgcn_s_barrier(); } while (0)

// ONE-PASS GEMM on GLOBALLY COMPACTED rows (r17 schedule): 128x256 tile,
// 4 waves, BK=32, LDS 64KB -> 2 blocks/CU. Tiles past nkeep exit at once.
// XCD-interleaved tile remap: each chunk gets stride-8 rt values so active
// tiles (rt < ~128) spread evenly over all 8 XCDs; ct-siblings stay adjacent.
__global__ __launch_bounds__(256, 2) void fused_gemm(
        const float* __restrict__ enc,  // [32768][2048] fp32
        const f16* __restrict__ weT,    // [4 ct][64 kt][16KB]
        const float* __restrict__ sdec, // [16][1024]
        const float* __restrict__ vw,   // [1024]
        const int* __restrict__ ridx,   // [32768] compacted -> source row
        const int* __restrict__ nkeep,  // nkeep[0] = total kept
        float* __restrict__ part)       // [NCT][32768] (compacted rows)
{
    const int lg = ((int)blockIdx.x & 7) * 128 + ((int)blockIdx.x >> 3);
    const int i4 = lg >> 2;
    const int ct = lg & 3;
    const int rt = ((i4 & 31) << 3) + (i4 >> 5);   // stride-8 interleave per chunk

    const int nk = nkeep[0];
    if (rt * 128 >= nk) return;      // uniform early exit (before any barrier)

    const int tid = threadIdx.x;
    const int l15 = tid & 15;
    const int l4  = (tid >> 4) & 3;
    const int wv  = tid >> 6;        // 0..3
    const int wm  = wv >> 1;         // 0..1  (64 rows each)
    const int wn  = wv & 1;          // 0..1  (128 cols each)

    __shared__ char lds[65536];      // A 2x8KB + B 3x16KB
    __shared__ float red[2][128];
    __shared__ int bArr[128];        // per-row batch (epilogue)

    const char* bT = (const char*)weT + ((size_t)ct << 20);

    // ---- A staging (gathered): thread -> compacted row rt*128 + (tid>>1) ----
    const int ar_ = tid >> 1;
    const int ah  = tid & 1;
    int cidx = rt * 128 + ar_;
    if (cidx >= nk) cidx = rt * 128;           // pad: clamp
    const int grow = ridx[cidx];               // global source row
    const float* aG = enc + (size_t)grow * KDIM + ah * 16;
    const int aswz = (ar_ >> 1) & 3;
    const int awb0 = ar_ * 64 + (((2 * ah)     ^ aswz) << 4);
    const int awb1 = ar_ * 64 + (((2 * ah + 1) ^ aswz) << 4);

    // ---- frag reads (r5-verified 0-conflict): row 64B, phys = l4^((row>>1)&3)
    const int fswz = (l4 ^ ((l15 >> 1) & 3)) << 4;
    const int aro = (wm * 64  + l15) * 64 + fswz;   // + i*1024, i=0..3
    const int bro = (wn * 128 + l15) * 64 + fswz;   // + j*1024, j=0..7

    f32x4 acc[4][8] = {};

    auto loadAreg = [&](float4 (&s)[4], int t) {
        const float* p = aG + (size_t)t * 32;
        s[0] = *(const float4*)(p);
        s[1] = *(const float4*)(p + 4);
        s[2] = *(const float4*)(p + 8);
        s[3] = *(const float4*)(p + 12);
    };
    auto writeA = [&](const float4 (&s)[4], int slot) {
        char* d = lds + A_OFF(slot);
        auto c0 = __builtin_amdgcn_cvt_pkrtz(s[0].x, s[0].y);
        auto c1 = __builtin_amdgcn_cvt_pkrtz(s[0].z, s[0].w);
        auto c2 = __builtin_amdgcn_cvt_pkrtz(s[1].x, s[1].y);
        auto c3 = __builtin_amdgcn_cvt_pkrtz(s[1].z, s[1].w);
        auto c4 = __builtin_amdgcn_cvt_pkrtz(s[2].x, s[2].y);
        auto c5 = __builtin_amdgcn_cvt_pkrtz(s[2].z, s[2].w);
        auto c6 = __builtin_amdgcn_cvt_pkrtz(s[3].x, s[3].y);
        auto c7 = __builtin_amdgcn_cvt_pkrtz(s[3].z, s[3].w);
        f16x8 h0 = { (f16)c0[0],(f16)c0[1],(f16)c1[0],(f16)c1[1],
                     (f16)c2[0],(f16)c2[1],(f16)c3[0],(f16)c3[1] };
        f16x8 h1 = { (f16)c4[0],(f16)c4[1],(f16)c5[0],(f16)c5[1],
                     (f16)c6[0],(f16)c6[1],(f16)c7[0],(f16)c7[1] };
        *(f16x8*)(d + awb0) = h0;
        *(f16x8*)(d + awb1) = h1;
    };
    auto stageB = [&](int t, int slot) {
        const char* s = bT + ((size_t)t << 14) + tid * 16;
        char* d = lds + B_OFF(slot) + tid * 16;
        gload16(s, d);               gload16(s + 4096, d + 4096);
        gload16(s + 8192, d + 8192); gload16(s + 12288, d + 12288);
    };

    int brS = 0, bwS = 2;

    auto body = [&](int t, float4 (&sIss)[4], float4 (&sCvt)[4]) {
        const char* sa = lds + A_OFF(t & 1);
        const char* sb = lds + B_OFF(brS);
        f16x8 fa[4], bf[4];
        // ---------- phase 0: all A frags + B j=0..3 ----------
        #pragma unroll
        for (int ii = 0; ii < 4; ++ii) fa[ii] = *(const f16x8*)(sa + aro + ii * 1024);
        #pragma unroll
        for (int j = 0; j < 4; ++j)  bf[j]  = *(const f16x8*)(sb + bro + j * 1024);
        if (t + 2 < NKT) loadAreg(sIss, t + 2);
        PH_OPEN;
        __builtin_amdgcn_s_setprio(1);
        #pragma unroll
        for (int ii = 0; ii < 4; ++ii)
            #pragma unroll
            for (int j = 0; j < 4; ++j)
                acc[ii][j] = __builtin_amdgcn_mfma_f32_16x16x32_f16(fa[ii], bf[j], acc[ii][j], 0, 0, 0);
        __builtin_amdgcn_s_setprio(0);
        PH_CLOSE;
        // ---------- phase 1: B j=4..7 ----------
        #pragma unroll
        for (int j = 0; j < 4; ++j) bf[j] = *(const f16x8*)(sb + bro + (4 + j) * 1024);
        if (t + 1 < NKT) writeA(sCvt, (t + 1) & 1);   // regs issued 1 iter ago
        if (t + 2 < NKT) stageB(t + 2, bwS);
        PH_OPEN;
        __builtin_amdgcn_s_setprio(1);
        #pragma unroll
        for (int ii = 0; ii < 4; ++ii)
            #pragma unroll
            for (int j = 0; j < 4; ++j)
                acc[ii][4 + j] = __builtin_amdgcn_mfma_f32_16x16x32_f16(fa[ii], bf[j], acc[ii][4 + j], 0, 0, 0);
        __builtin_amdgcn_s_setprio(0);
        if (t < NKT - 2) { asm volatile("s_waitcnt vmcnt(8)" ::: "memory"); }
        else             { asm volatile("s_waitcnt vmcnt(0)" ::: "memory"); }
        PH_CLOSE;
        brS = (brS == 2) ? 0 : brS + 1;
        bwS = (bwS == 2) ? 0 : bwS + 1;
    };

    float4 sEven[4], sOdd[4];
    loadAreg(sEven, 0);
    writeA(sEven, 0);
    loadAreg(sOdd, 1);
    stageB(0, 0); stageB(1, 1);
    asm volatile("s_waitcnt lgkmcnt(0)" ::: "memory");
    asm volatile("s_waitcnt vmcnt(4)" ::: "memory");
    __builtin_amdgcn_s_barrier();
    __builtin_amdgcn_sched_barrier(0);

    #pragma unroll 1
    for (int tt = 0; tt < NKT; tt += 2) {
        body(tt,     sEven, sOdd);
        body(tt + 1, sOdd,  sEven);
    }

    // ---------------- epilogue ----------------
    const int colbase = ct * 256;

    __syncthreads();
    if (tid < 128) {
        int ci = rt * 128 + tid;
        if (ci >= nk) ci = rt * 128;
        bArr[tid] = ridx[ci] >> 11;    // batch of this compacted row
    }
    __syncthreads();

    float vs[8];
    int colv[8];
    #pragma unroll
    for (int j = 0; j < 8; ++j) {
        colv[j] = colbase + wn * 128 + j * 16 + l15;
        vs[j] = vw[colv[j]];
    }
    float psum[4][4] = {};
    #pragma unroll
    for (int i = 0; i < 4; ++i)
        #pragma unroll
        for (int q = 0; q < 4; ++q) {
            const int b_ = bArr[wm * 64 + i * 16 + l4 * 4 + q];
            const float* sdr = sdec + b_ * 1024;
            #pragma unroll
            for (int j = 0; j < 8; ++j)
                psum[i][q] += tanh_mul(acc[i][j][q] + sdr[colv[j]], vs[j]);
        }

    #pragma unroll
    for (int i = 0; i < 4; ++i)
        #pragma unroll
        for (int q = 0; q < 4; ++q) {
            float s = psum[i][q];
            s += __shfl_xor(s, 1); s += __shfl_xor(s, 2);
            s += __shfl_xor(s, 4); s += __shfl_xor(s, 8);
            psum[i][q] = s;
        }

    __syncthreads();
    if (l15 == 0) {
        #pragma unroll
        for (int i = 0; i < 4; ++i)
            #pragma unroll
            for (int q = 0; q < 4; ++q)
                red[wn][wm * 64 + i * 16 + l4 * 4 + q] = psum[i][q];
    }
    __syncthreads();
    if (tid < 128)
        part[(size_t)ct * M_TOT + rt * 128 + tid] = red[0][tid] + red[1][tid];
}

// softmax over L per batch; pos<0 -> -1e10; else sum NCT partials at global
// compacted row.
__global__ __launch_bounds__(512) void softmax_kernel(
        const float* __restrict__ part, const int* __restrict__ pos,
        float* __restrict__ out) {
    int b = blockIdx.x;
    int tid = threadIdx.x;
    int lane = tid & 63, w = tid >> 6;
    __shared__ float sred[8];

    float vals[4];
    #pragma unroll
    for (int p = 0; p < 4; ++p) {
        int row = b * LSEQ + tid + p * 512;
        int pp = pos[row];
        float val = NEG_INF_F;
        if (pp >= 0) {
            val = 0.f;
            #pragma unroll
            for (int q = 0; q < NCT; ++q) val += part[(size_t)q * M_TOT + pp];
        }
        vals[p] = val;
    }
    float mx = fmaxf(fmaxf(vals[0], vals[1]), fmaxf(vals[2], vals[3]));
    #pragma unroll
    for (int m = 1; m < 64; m <<= 1) mx = fmaxf(mx, __shfl_xor(mx, m));
    if (lane == 0) sred[w] = mx;
    __syncthreads();
    float gmax = sred[0];
    #pragma unroll
    for (int i = 1; i < 8; ++i) gmax = fmaxf(gmax, sred[i]);

    float es[4]; float ssum = 0.f;
    #pragma unroll
    for (int p = 0; p < 4; ++p) { es[p] = expf(vals[p] - gmax); ssum += es[p]; }
    #pragma unroll
    for (int m = 1; m < 64; m <<= 1) ssum += __shfl_xor(ssum, m);
    __syncthreads();
    if (lane == 0) sred[w] = ssum;
    __syncthreads();
    float gsum = 0.f;
    #pragma unroll
    for (int i = 0; i < 8; ++i) gsum += sred[i];
    float inv = 1.f / gsum;
    #pragma unroll
    for (int p = 0; p < 4; ++p)
        out[b * LSEQ + tid + p * 512] = es[p] * inv;
}

extern "C" void kernel_launch(void* const* d_in, const int* in_sizes, int n_in,
                              void* d_out, int out_size, void* d_ws, size_t ws_size,
                              hipStream_t stream) {
    const float* enc    = (const float*)d_in[0];
    const int*   mask   = (const int*)  d_in[1];
    const float* v      = (const float*)d_in[2];
    const float* attn_w = (const float*)d_in[3];
    const float* attn_b = (const float*)d_in[4];
    const float* v_w    = (const float*)d_in[5];
    float* out = (float*)d_out;

    char* ws = (char*)d_ws;
    float* sdec  = (float*)(ws + WS_SDEC_OFF);
    float* part  = (float*)(ws + WS_PART_OFF);
    int*   pos   = (int*)  (ws + WS_POS_OFF);
    int*   ridx  = (int*)  (ws + WS_RIDX_OFF);
    int*   nkeep = (int*)  (ws + WS_NKEEP_OFF);
    f16*   weT   = (f16*)  (ws + WS_WET_OFF);

    hipLaunchKernelGGL(prep_kernel,    dim3(513),  dim3(256), 0, stream,
                       attn_w, weT, v, attn_b, sdec, mask, ridx, pos, nkeep);
    hipLaunchKernelGGL(fused_gemm,     dim3(1024), dim3(256), 0, stream,
                       enc, weT, sdec, v_w, ridx, nkeep, part);
    hipLaunchKernelGGL(softmax_kernel, dim3(16),   dim3(512), 0, stream, part, pos, out);
}

// Round 21
// 141.406 us; speedup vs baseline: 1.3240x; 1.3240x over previous
//
#include <hip/hip_runtime.h>
#include <stdint.h>

#define LSEQ 2048
#define M_TOT 32768          // B*L
#define KDIM 2048            // 2H
#define NKT 64               // K tiles of 32
#define NCT 4                // col tiles of 256
#define NEG_INF_F (-10000000000.0f)

typedef _Float16 f16;
typedef f16 f16x8 __attribute__((ext_vector_type(8)));
typedef float f32x4 __attribute__((ext_vector_type(4)));

// ---------------- ws layout ----------------
// [0, 64K)       sdec f32[16][1024]
// [64K, 576K)    part f32[4][32768]
// [576K, 704K)   pos  int[32768]   (batch-local compacted position or -1)
// [704K, 832K)   ridx int[32768]   (per-batch: ridx[b*2048+p] = global row)
// [832K, 833K)   nkeep int[16]
// [2M, 6M)       weT  tiled fp16 B [4 ct][64 kt][1024 granules x 16B]
#define WS_SDEC_OFF  0
#define WS_PART_OFF  (64u << 10)
#define WS_POS_OFF   (576u << 10)
#define WS_RIDX_OFF  (704u << 10)
#define WS_NKEEP_OFF (832u << 10)
#define WS_WET_OFF   (2u << 20)

// LDS: A 2 slots x 8KB + B 3 slots x 16KB = 64KB  -> 2 blocks/CU
#define A_OFF(s) ((s) * 8192)
#define B_OFF(s) (16384 + (s) * 16384)

__device__ inline void gload16(const void* g, void* l) {
    __builtin_amdgcn_global_load_lds(
        (const __attribute__((address_space(1))) void*)g,
        (__attribute__((address_space(3))) void*)l, 16, 0, 0);
}

// fast tanh(x)*s with sign fold
__device__ inline float tanh_mul(float x, float s) {
    float ax = __builtin_fabsf(x);
    float e  = __expf(-2.f * ax);
    float th = (1.f - e) * __builtin_amdgcn_rcpf(1.f + e);
    float sv = __uint_as_float(__float_as_uint(s) ^ (__float_as_uint(x) & 0x80000000u));
    return th * sv;
}

// MERGED PREP: blocks [0,256) wecvt | [256,512) sdec (h-major) |
// [512,528) per-batch compact (parallel, r18-style).
__global__ __launch_bounds__(256) void prep_kernel(
        const float* __restrict__ attn_w, f16* __restrict__ weT,
        const float* __restrict__ v, const float* __restrict__ attn_b,
        float* __restrict__ sdec,
        const int* __restrict__ mask, int* __restrict__ ridx,
        int* __restrict__ pos, int* __restrict__ nkeep) {
    const int blk = blockIdx.x;
    const int tid = threadIdx.x;
    __shared__ int wsum[4];

    if (blk < 256) {
        // ---- wecvt: W_e -> tiled fp16 B, r5-verified 0-conflict swizzle ----
        int g = blk * 1024 + tid;
        #pragma unroll
        for (int q = 0; q < 4; ++q, g += 256) {
            int ct  = g >> 16;
            int rem = g & 65535;
            int kt  = rem >> 10;
            int p   = rem & 1023;
            int row = p >> 2;
            int sl  = (p & 3) ^ ((row >> 1) & 3);
            const float* s = attn_w + (size_t)(ct * 256 + row) * 3072 + 1024 + kt * 32 + sl * 8;
            float4 a = *(const float4*)s;
            float4 b = *(const float4*)(s + 4);
            f16x8 h = { (f16)a.x,(f16)a.y,(f16)a.z,(f16)a.w,(f16)b.x,(f16)b.y,(f16)b.z,(f16)b.w };
            *(f16x8*)(weT + (size_t)g * 8) = h;
        }
    } else if (blk < 512) {
        // ---- sdec, h-major: one wave per h, loop 16 batches (W_v read once) ----
        const int h = (blk - 256) * 4 + (tid >> 6);
        const int lane = tid & 63;
        const float* wr = attn_w + (size_t)h * 3072;
        float s[16];
        #pragma unroll
        for (int b = 0; b < 16; ++b) s[b] = 0.f;
        for (int k = 0; k < 16; ++k) {
            const int idx = lane + 64 * k;
            const float w_ = wr[idx];
            #pragma unroll
            for (int b = 0; b < 16; ++b) s[b] += v[b * 1024 + idx] * w_;
        }
        const float bias = attn_b[h];
        #pragma unroll
        for (int b = 0; b < 16; ++b) {
            float t = s[b];
            #pragma unroll
            for (int m = 1; m < 64; m <<= 1) t += __shfl_xor(t, m);
            if (lane == 0) sdec[b * 1024 + h] = t + bias;
        }
    } else {
        // ---- per-batch compact: 256 thr x 8 rows (parallel across 16 blocks) ----
        const int b = blk - 512;
        const int lane = tid & 63, w = tid >> 6;
        const int base = b * 2048 + tid * 8;
        int m[8], cnt = 0;
        #pragma unroll
        for (int i = 0; i < 8; ++i) { m[i] = mask[base + i] != 0; cnt += m[i]; }
        int inc = cnt;
        #pragma unroll
        for (int d = 1; d < 64; d <<= 1) {
            int t = __shfl_up(inc, d);
            if (lane >= d) inc += t;
        }
        if (lane == 63) wsum[w] = inc;
        __syncthreads();
        int wbase = 0, total = 0;
        #pragma unroll
        for (int i = 0; i < 4; ++i) { if (i < w) wbase += wsum[i]; total += wsum[i]; }
        int p = wbase + inc - cnt;   // exclusive prefix (batch-local)
        #pragma unroll
        for (int i = 0; i < 8; ++i) {
            if (m[i]) { ridx[b * 2048 + p] = base + i; pos[base + i] = p; p++; }
            else      { pos[base + i] = -1; }
        }
        if (tid == 0) nkeep[b] = total;
    }
}

#define PH_OPEN  do { __builtin_amdgcn_sched_barrier(0); __builtin_amdgcn_s_barrier(); \
                      asm volatile("s_waitcnt lgkmcnt(0)" ::: "memory"); \
                      __builtin_amdgcn_sched_barrier(0); } while (0)
#define PH_CLOSE do { __builtin_amdgcn_sched_barrier(0); __builtin_amdgcn_s_barrier(); } while (0)

// ONE-PASS GEMM on GLOBALLY-TILED compacted rows (r17 schedule): 128x256 tile,
// 4 waves, BK=32, LDS 64KB -> 2 blocks/CU. Global slot space derived from the
// 16 per-batch nkeep values (register prefix); tiles past total exit at once.
__global__ __launch_bounds__(256, 2) void fused_gemm(
        const float* __restrict__ enc,  // [32768][2048] fp32
        const f16* __restrict__ weT,    // [4 ct][64 kt][16KB]
        const float* __restrict__ sdec, // [16][1024]
        const float* __restrict__ vw,   // [1024]
        const int* __restrict__ ridx,   // per-batch compacted -> source row
        const int* __restrict__ nkeep,  // [16]
        float* __restrict__ part)       // [NCT][32768] (global slots)
{
    const int lg = ((int)blockIdx.x & 7) * 128 + ((int)blockIdx.x >> 3);
    const int i4 = lg >> 2;
    const int ct = lg & 3;
    const int rt = ((i4 & 31) << 3) + (i4 >> 5);   // stride-8 interleave per chunk

    // global bases from per-batch counts
    int base[17];
    base[0] = 0;
    #pragma unroll
    for (int b = 0; b < 16; ++b) base[b + 1] = base[b] + nkeep[b];
    const int total = base[16];
    if (rt * 128 >= total) return;   // uniform early exit (before any barrier)

    const int tid = threadIdx.x;
    const int l15 = tid & 15;
    const int l4  = (tid >> 4) & 3;
    const int wv  = tid >> 6;        // 0..3
    const int wm  = wv >> 1;         // 0..1  (64 rows each)
    const int wn  = wv & 1;          // 0..1  (128 cols each)

    __shared__ char lds[65536];      // A 2x8KB + B 3x16KB
    __shared__ float red[2][128];
    __shared__ int bArr[128];        // per-row batch (epilogue)

    const char* bT = (const char*)weT + ((size_t)ct << 20);

    // ---- A staging (gathered): thread -> global slot rt*128 + (tid>>1) ----
    const int ar_ = tid >> 1;
    const int ah  = tid & 1;
    int g = rt * 128 + ar_;
    if (g >= total) g = rt * 128;              // pad: clamp (valid, tile active)
    int gb = 0;
    #pragma unroll
    for (int b = 1; b < 16; ++b) if (g >= base[b]) gb = b;
    const int grow = ridx[gb * 2048 + (g - base[gb])];
    const float* aG = enc + (size_t)grow * KDIM + ah * 16;
    const int aswz = (ar_ >> 1) & 3;
    const int awb0 = ar_ * 64 + (((2 * ah)     ^ aswz) << 4);
    const int awb1 = ar_ * 64 + (((2 * ah + 1) ^ aswz) << 4);

    // ---- frag reads (r5-verified 0-conflict): row 64B, phys = l4^((row>>1)&3)
    const int fswz = (l4 ^ ((l15 >> 1) & 3)) << 4;
    const int aro = (wm * 64  + l15) * 64 + fswz;   // + i*1024, i=0..3
    const int bro = (wn * 128 + l15) * 64 + fswz;   // + j*1024, j=0..7

    f32x4 acc[4][8] = {};

    auto loadAreg = [&](float4 (&s)[4], int t) {
        const float* p = aG + (size_t)t * 32;
        s[0] = *(const float4*)(p);
        s[1] = *(const float4*)(p + 4);
        s[2] = *(const float4*)(p + 8);
        s[3] = *(const float4*)(p + 12);
    };
    auto writeA = [&](const float4 (&s)[4], int slot) {
        char* d = lds + A_OFF(slot);
        auto c0 = __builtin_amdgcn_cvt_pkrtz(s[0].x, s[0].y);
        auto c1 = __builtin_amdgcn_cvt_pkrtz(s[0].z, s[0].w);
        auto c2 = __builtin_amdgcn_cvt_pkrtz(s[1].x, s[1].y);
        auto c3 = __builtin_amdgcn_cvt_pkrtz(s[1].z, s[1].w);
        auto c4 = __builtin_amdgcn_cvt_pkrtz(s[2].x, s[2].y);
        auto c5 = __builtin_amdgcn_cvt_pkrtz(s[2].z, s[2].w);
        auto c6 = __builtin_amdgcn_cvt_pkrtz(s[3].x, s[3].y);
        auto c7 = __builtin_amdgcn_cvt_pkrtz(s[3].z, s[3].w);
        f16x8 h0 = { (f16)c0[0],(f16)c0[1],(f16)c1[0],(f16)c1[1],
                     (f16)c2[0],(f16)c2[1],(f16)c3[0],(f16)c3[1] };
        f16x8 h1 = { (f16)c4[0],(f16)c4[1],(f16)c5[0],(f16)c5[1],
                     (f16)c6[0],(f16)c6[1],(f16)c7[0],(f16)c7[1] };
        *(f16x8*)(d + awb0) = h0;
        *(f16x8*)(d + awb1) = h1;
    };
    auto stageB = [&](int t, int slot) {
        const char* s = bT + ((size_t)t << 14) + tid * 16;
        char* d = lds + B_OFF(slot) + tid * 16;
        gload16(s, d);               gload16(s + 4096, d + 4096);
        gload16(s + 8192, d + 8192); gload16(s + 12288, d + 12288);
    };

    int brS = 0, bwS = 2;

    auto body = [&](int t, float4 (&sIss)[4], float4 (&sCvt)[4]) {
        const char* sa = lds + A_OFF(t & 1);
        const char* sb = lds + B_OFF(brS);
        f16x8 fa[4], bf[4];
        // ---------- phase 0: all A frags + B j=0..3 ----------
        #pragma unroll
        for (int ii = 0; ii < 4; ++ii) fa[ii] = *(const f16x8*)(sa + aro + ii * 1024);
        #pragma unroll
        for (int j = 0; j < 4; ++j)  bf[j]  = *(const f16x8*)(sb + bro + j * 1024);
        if (t + 2 < NKT) loadAreg(sIss, t + 2);
        PH_OPEN;
        __builtin_amdgcn_s_setprio(1);
        #pragma unroll
        for (int ii = 0; ii < 4; ++ii)
            #pragma unroll
            for (int j = 0; j < 4; ++j)
                acc[ii][j] = __builtin_amdgcn_mfma_f32_16x16x32_f16(fa[ii], bf[j], acc[ii][j], 0, 0, 0);
        __builtin_amdgcn_s_setprio(0);
        PH_CLOSE;
        // ---------- phase 1: B j=4..7 ----------
        #pragma unroll
        for (int j = 0; j < 4; ++j) bf[j] = *(const f16x8*)(sb + bro + (4 + j) * 1024);
        if (t + 1 < NKT) writeA(sCvt, (t + 1) & 1);   // regs issued 1 iter ago
        if (t + 2 < NKT) stageB(t + 2, bwS);
        PH_OPEN;
        __builtin_amdgcn_s_setprio(1);
        #pragma unroll
        for (int ii = 0; ii < 4; ++ii)
            #pragma unroll
            for (int j = 0; j < 4; ++j)
                acc[ii][4 + j] = __builtin_amdgcn_mfma_f32_16x16x32_f16(fa[ii], bf[j], acc[ii][4 + j], 0, 0, 0);
        __builtin_amdgcn_s_setprio(0);
        if (t < NKT - 2) { asm volatile("s_waitcnt vmcnt(8)" ::: "memory"); }
        else             { asm volatile("s_waitcnt vmcnt(0)" ::: "memory"); }
        PH_CLOSE;
        brS = (brS == 2) ? 0 : brS + 1;
        bwS = (bwS == 2) ? 0 : bwS + 1;
    };

    float4 sEven[4], sOdd[4];
    loadAreg(sEven, 0);
    writeA(sEven, 0);
    loadAreg(sOdd, 1);
    stageB(0, 0); stageB(1, 1);
    asm volatile("s_waitcnt lgkmcnt(0)" ::: "memory");
    asm volatile("s_waitcnt vmcnt(4)" ::: "memory");
    __builtin_amdgcn_s_barrier();
    __builtin_amdgcn_sched_barrier(0);

    #pragma unroll 1
    for (int tt = 0; tt < NKT; tt += 2) {
        body(tt,     sEven, sOdd);
        body(tt + 1, sOdd,  sEven);
    }

    // ---------------- epilogue ----------------
    const int colbase = ct * 256;

    __syncthreads();
    if (tid < 128) {
        int gi = rt * 128 + tid;
        if (gi >= total) gi = rt * 128;
        int bb = 0;
        #pragma unroll
        for (int b = 1; b < 16; ++b) if (gi >= base[b]) bb = b;
        bArr[tid] = bb;
    }
    __syncthreads();

    float vs[8];
    int colv[8];
    #pragma unroll
    for (int j = 0; j < 8; ++j) {
        colv[j] = colbase + wn * 128 + j * 16 + l15;
        vs[j] = vw[colv[j]];
    }
    float psum[4][4] = {};
    #pragma unroll
    for (int i = 0; i < 4; ++i)
        #pragma unroll
        for (int q = 0; q < 4; ++q) {
            const int b_ = bArr[wm * 64 + i * 16 + l4 * 4 + q];
            const float* sdr = sdec + b_ * 1024;
            #pragma unroll
            for (int j = 0; j < 8; ++j)
                psum[i][q] += tanh_mul(acc[i][j][q] + sdr[colv[j]], vs[j]);
        }

    #pragma unroll
    for (int i = 0; i < 4; ++i)
        #pragma unroll
        for (int q = 0; q < 4; ++q) {
            float s = psum[i][q];
            s += __shfl_xor(s, 1); s += __shfl_xor(s, 2);
            s += __shfl_xor(s, 4); s += __shfl_xor(s, 8);
            psum[i][q] = s;
        }

    __syncthreads();
    if (l15 == 0) {
        #pragma unroll
        for (int i = 0; i < 4; ++i)
            #pragma unroll
            for (int q = 0; q < 4; ++q)
                red[wn][wm * 64 + i * 16 + l4 * 4 + q] = psum[i][q];
    }
    __syncthreads();
    if (tid < 128)
        part[(size_t)ct * M_TOT + rt * 128 + tid] = red[0][tid] + red[1][tid];
}

// softmax over L per batch; pos<0 -> -1e10; global slot = base[b] + pos.
__global__ __launch_bounds__(512) void softmax_kernel(
        const float* __restrict__ part, const int* __restrict__ pos,
        const int* __restrict__ nkeep, float* __restrict__ out) {
    int b = blockIdx.x;
    int tid = threadIdx.x;
    int lane = tid & 63, w = tid >> 6;
    __shared__ float sred[8];

    int gbase = 0;
    #pragma unroll
    for (int i = 0; i < 16; ++i) if (i < b) gbase += nkeep[i];

    float vals[4];
    #pragma unroll
    for (int p = 0; p < 4; ++p) {
        int row = b * LSEQ + tid + p * 512;
        int pp = pos[row];
        float val = NEG_INF_F;
        if (pp >= 0) {
            int slot = gbase + pp;
            val = 0.f;
            #pragma unroll
            for (int q = 0; q < NCT; ++q) val += part[(size_t)q * M_TOT + slot];
        }
        vals[p] = val;
    }
    float mx = fmaxf(fmaxf(vals[0], vals[1]), fmaxf(vals[2], vals[3]));
    #pragma unroll
    for (int m = 1; m < 64; m <<= 1) mx = fmaxf(mx, __shfl_xor(mx, m));
    if (lane == 0) sred[w] = mx;
    __syncthreads();
    float gmax = sred[0];
    #pragma unroll
    for (int i = 1; i < 8; ++i) gmax = fmaxf(gmax, sred[i]);

    float es[4]; float ssum = 0.f;
    #pragma unroll
    for (int p = 0; p < 4; ++p) { es[p] = expf(vals[p] - gmax); ssum += es[p]; }
    #pragma unroll
    for (int m = 1; m < 64; m <<= 1) ssum += __shfl_xor(ssum, m);
    __syncthreads();
    if (lane == 0) sred[w] = ssum;
    __syncthreads();
    float gsum = 0.f;
    #pragma unroll
    for (int i = 0; i < 8; ++i) gsum += sred[i];
    float inv = 1.f / gsum;
    #pragma unroll
    for (int p = 0; p < 4; ++p)
        out[b * LSEQ + tid + p * 512] = es[p] * inv;
}

extern "C" void kernel_launch(void* const* d_in, const int* in_sizes, int n_in,
                              void* d_out, int out_size, void* d_ws, size_t ws_size,
                              hipStream_t stream) {
    const float* enc    = (const float*)d_in[0];
    const int*   mask   = (const int*)  d_in[1];
    const float* v      = (const float*)d_in[2];
    const float* attn_w = (const float*)d_in[3];
    const float* attn_b = (const float*)d_in[4];
    const float* v_w    = (const float*)d_in[5];
    float* out = (float*)d_out;

    char* ws = (char*)d_ws;
    float* sdec  = (float*)(ws + WS_SDEC_OFF);
    float* part  = (float*)(ws + WS_PART_OFF);
    int*   pos   = (int*)  (ws + WS_POS_OFF);
    int*   ridx  = (int*)  (ws + WS_RIDX_OFF);
    int*   nkeep = (int*)  (ws + WS_NKEEP_OFF);
    f16*   weT   = (f16*)  (ws + WS_WET_OFF);

    hipLaunchKernelGGL(prep_kernel,    dim3(528),  dim3(256), 0, stream,
                       attn_w, weT, v, attn_b, sdec, mask, ridx, pos, nkeep);
    hipLaunchKernelGGL(fused_gemm,     dim3(1024), dim3(256), 0, stream,
                       enc, weT, sdec, v_w, ridx, nkeep, part);
    hipLaunchKernelGGL(softmax_kernel, dim3(16),   dim3(512), 0, stream,
                       part, pos, nkeep, out);
}

// Round 22
// 136.037 us; speedup vs baseline: 1.3763x; 1.0395x over previous
//
#include <hip/hip_runtime.h>
#include <stdint.h>

#define LSEQ 2048
#define M_TOT 32768          // B*L
#define KDIM 2048            // 2H
#define NKT 64               // K tiles of 32
#define NCT 4                // col tiles of 256
#define NEG_INF_F (-10000000000.0f)

typedef _Float16 f16;
typedef f16 f16x8 __attribute__((ext_vector_type(8)));
typedef float f32x4 __attribute__((ext_vector_type(4)));

// ---------------- ws layout ----------------
// [0, 64K)       sdec f32[16][1024]
// [64K, 576K)    part f32[4][32768]
// [576K, 704K)   pos  int[32768]
// [704K, 832K)   ridx int[32768]
// [832K, 833K)   nkeep int[16]
// [2M, 6M)       weT  tiled fp16 B [4 ct][64 kt][1024 granules x 16B]
#define WS_SDEC_OFF  0
#define WS_PART_OFF  (64u << 10)
#define WS_POS_OFF   (576u << 10)
#define WS_RIDX_OFF  (704u << 10)
#define WS_NKEEP_OFF (832u << 10)
#define WS_WET_OFF   (2u << 20)

// LDS: A 2 slots x 8KB + B 3 slots x 16KB = 64KB  -> 2 blocks/CU
#define A_OFF(s) ((s) * 8192)
#define B_OFF(s) (16384 + (s) * 16384)

__device__ inline void gload16(const void* g, void* l) {
    __builtin_amdgcn_global_load_lds(
        (const __attribute__((address_space(1))) void*)g,
        (__attribute__((address_space(3))) void*)l, 16, 0, 0);
}

// fast tanh(x)*s with sign fold
__device__ inline float tanh_mul(float x, float s) {
    float ax = __builtin_fabsf(x);
    float e  = __expf(-2.f * ax);
    float th = (1.f - e) * __builtin_amdgcn_rcpf(1.f + e);
    float sv = __uint_as_float(__float_as_uint(s) ^ (__float_as_uint(x) & 0x80000000u));
    return th * sv;
}

// MERGED PREP: blocks [0,256) wecvt | [256,512) sdec (h-major) | [512,528) compact.
__global__ __launch_bounds__(256) void prep_kernel(
        const float* __restrict__ attn_w, f16* __restrict__ weT,
        const float* __restrict__ v, const float* __restrict__ attn_b,
        float* __restrict__ sdec,
        const int* __restrict__ mask, int* __restrict__ ridx,
        int* __restrict__ pos, int* __restrict__ nkeep) {
    const int blk = blockIdx.x;
    const int tid = threadIdx.x;
    __shared__ int wsum[4];

    if (blk < 256) {
        // ---- wecvt: W_e -> tiled fp16 B, r5-verified 0-conflict swizzle ----
        int g = blk * 1024 + tid;
        #pragma unroll
        for (int q = 0; q < 4; ++q, g += 256) {
            int ct  = g >> 16;
            int rem = g & 65535;
            int kt  = rem >> 10;
            int p   = rem & 1023;
            int row = p >> 2;
            int sl  = (p & 3) ^ ((row >> 1) & 3);
            const float* s = attn_w + (size_t)(ct * 256 + row) * 3072 + 1024 + kt * 32 + sl * 8;
            float4 a = *(const float4*)s;
            float4 b = *(const float4*)(s + 4);
            f16x8 h = { (f16)a.x,(f16)a.y,(f16)a.z,(f16)a.w,(f16)b.x,(f16)b.y,(f16)b.z,(f16)b.w };
            *(f16x8*)(weT + (size_t)g * 8) = h;
        }
    } else if (blk < 512) {
        // ---- sdec, h-major: one wave per h, loop 16 batches (W_v read once) ----
        const int h = (blk - 256) * 4 + (tid >> 6);
        const int lane = tid & 63;
        const float* wr = attn_w + (size_t)h * 3072;
        float s[16];
        #pragma unroll
        for (int b = 0; b < 16; ++b) s[b] = 0.f;
        for (int k = 0; k < 16; ++k) {
            const int idx = lane + 64 * k;
            const float w_ = wr[idx];
            #pragma unroll
            for (int b = 0; b < 16; ++b) s[b] += v[b * 1024 + idx] * w_;
        }
        const float bias = attn_b[h];
        #pragma unroll
        for (int b = 0; b < 16; ++b) {
            float t = s[b];
            #pragma unroll
            for (int m = 1; m < 64; m <<= 1) t += __shfl_xor(t, m);
            if (lane == 0) sdec[b * 1024 + h] = t + bias;
        }
    } else {
        // ---- per-batch compact: 256 thr x 8 rows (parallel across 16 blocks) ----
        const int b = blk - 512;
        const int lane = tid & 63, w = tid >> 6;
        const int base = b * 2048 + tid * 8;
        int m[8], cnt = 0;
        #pragma unroll
        for (int i = 0; i < 8; ++i) { m[i] = mask[base + i] != 0; cnt += m[i]; }
        int inc = cnt;
        #pragma unroll
        for (int d = 1; d < 64; d <<= 1) {
            int t = __shfl_up(inc, d);
            if (lane >= d) inc += t;
        }
        if (lane == 63) wsum[w] = inc;
        __syncthreads();
        int wbase = 0, total = 0;
        #pragma unroll
        for (int i = 0; i < 4; ++i) { if (i < w) wbase += wsum[i]; total += wsum[i]; }
        int p = wbase + inc - cnt;   // exclusive prefix (batch-local)
        #pragma unroll
        for (int i = 0; i < 8; ++i) {
            if (m[i]) { ridx[b * 2048 + p] = base + i; pos[base + i] = p; p++; }
            else      { pos[base + i] = -1; }
        }
        if (tid == 0) nkeep[b] = total;
    }
}

#define PH_OPEN  do { __builtin_amdgcn_sched_barrier(0); __builtin_amdgcn_s_barrier(); \
                      asm volatile("s_waitcnt lgkmcnt(0)" ::: "memory"); \
                      __builtin_amdgcn_sched_barrier(0); } while (0)
#define PH_CLOSE do { __builtin_amdgcn_sched_barrier(0); __builtin_amdgcn_s_barrier(); } while (0)

// ONE-PASS GEMM on per-batch COMPACTED rows (r17 schedule): 128x256 tile,
// 4 waves, BK=32, LDS 64KB -> 2 blocks/CU. Tiles past nkeep[b] exit at once.
__global__ __launch_bounds__(256, 2) void fused_gemm(
        const float* __restrict__ enc,  // [32768][2048] fp32
        const f16* __restrict__ weT,    // [4 ct][64 kt][16KB]
        const float* __restrict__ sdec, // [16][1024]
        const float* __restrict__ vw,   // [1024]
        const int* __restrict__ ridx,   // [32768] per-batch compacted -> row
        const int* __restrict__ nkeep,  // [16]
        float* __restrict__ part)       // [NCT][32768] (compacted rows)
{
    // chunked XCD remap: 1024 blocks, 128/XCD; 4 ct-siblings of one rt adjacent
    const int logical = ((int)blockIdx.x & 7) * 128 + ((int)blockIdx.x >> 3);
    const int rt = logical >> 2;     // 0..255
    const int ct = logical & 3;

    const int b  = rt >> 4;          // batch
    const int rl = rt & 15;          // tile within batch (128 compacted rows)
    const int nk = nkeep[b];
    if (rl * 128 >= nk) return;      // uniform early exit (before any barrier)

    const int tid = threadIdx.x;
    const int l15 = tid & 15;
    const int l4  = (tid >> 4) & 3;
    const int wv  = tid >> 6;        // 0..3
    const int wm  = wv >> 1;         // 0..1  (64 rows each)
    const int wn  = wv & 1;          // 0..1  (128 cols each)

    __shared__ char lds[65536];      // A 2x8KB + B 3x16KB
    __shared__ float red[2][128];

    const char* bT = (const char*)weT + ((size_t)ct << 20);

    // ---- A staging (gathered): thread -> compacted row rl*128 + (tid>>1) ----
    const int ar_ = tid >> 1;
    const int ah  = tid & 1;
    int cidx = rl * 128 + ar_;
    if (cidx >= nk) cidx = rl * 128;           // pad: clamp to first row of tile
    const int grow = ridx[b * 2048 + cidx];    // global source row
    const float* aG = enc + (size_t)grow * KDIM + ah * 16;
    const int aswz = (ar_ >> 1) & 3;
    const int awb0 = ar_ * 64 + (((2 * ah)     ^ aswz) << 4);
    const int awb1 = ar_ * 64 + (((2 * ah + 1) ^ aswz) << 4);

    // ---- frag reads (r5-verified 0-conflict): row 64B, phys = l4^((row>>1)&3)
    const int fswz = (l4 ^ ((l15 >> 1) & 3)) << 4;
    const int aro = (wm * 64  + l15) * 64 + fswz;   // + i*1024, i=0..3
    const int bro = (wn * 128 + l15) * 64 + fswz;   // + j*1024, j=0..7

    f32x4 acc[4][8] = {};

    auto loadAreg = [&](float4 (&s)[4], int t) {
        const float* p = aG + (size_t)t * 32;
        s[0] = *(const float4*)(p);
        s[1] = *(const float4*)(p + 4);
        s[2] = *(const float4*)(p + 8);
        s[3] = *(const float4*)(p + 12);
    };
    auto writeA = [&](const float4 (&s)[4], int slot) {
        char* d = lds + A_OFF(slot);
        auto c0 = __builtin_amdgcn_cvt_pkrtz(s[0].x, s[0].y);
        auto c1 = __builtin_amdgcn_cvt_pkrtz(s[0].z, s[0].w);
        auto c2 = __builtin_amdgcn_cvt_pkrtz(s[1].x, s[1].y);
        auto c3 = __builtin_amdgcn_cvt_pkrtz(s[1].z, s[1].w);
        auto c4 = __builtin_amdgcn_cvt_pkrtz(s[2].x, s[2].y);
        auto c5 = __builtin_amdgcn_cvt_pkrtz(s[2].z, s[2].w);
        auto c6 = __builtin_amdgcn_cvt_pkrtz(s[3].x, s[3].y);
        auto c7 = __builtin_amdgcn_cvt_pkrtz(s[3].z, s[3].w);
        f16x8 h0 = { (f16)c0[0],(f16)c0[1],(f16)c1[0],(f16)c1[1],
                     (f16)c2[0],(f16)c2[1],(f16)c3[0],(f16)c3[1] };
        f16x8 h1 = { (f16)c4[0],(f16)c4[1],(f16)c5[0],(f16)c5[1],
                     (f16)c6[0],(f16)c6[1],(f16)c7[0],(f16)c7[1] };
        *(f16x8*)(d + awb0) = h0;
        *(f16x8*)(d + awb1) = h1;
    };
    auto stageB = [&](int t, int slot) {
        const char* s = bT + ((size_t)t << 14) + tid * 16;
        char* d = lds + B_OFF(slot) + tid * 16;
        gload16(s, d);               gload16(s + 4096, d + 4096);
        gload16(s + 8192, d + 8192); gload16(s + 12288, d + 12288);
    };

    int brS = 0, bwS = 2;

    auto body = [&](int t, float4 (&sIss)[4], float4 (&sCvt)[4]) {
        const char* sa = lds + A_OFF(t & 1);
        const char* sb = lds + B_OFF(brS);
        f16x8 fa[4], bf[4];
        // ---------- phase 0: all A frags + B j=0..3 ----------
        #pragma unroll
        for (int ii = 0; ii < 4; ++ii) fa[ii] = *(const f16x8*)(sa + aro + ii * 1024);
        #pragma unroll
        for (int j = 0; j < 4; ++j)  bf[j]  = *(const f16x8*)(sb + bro + j * 1024);
        if (t + 2 < NKT) loadAreg(sIss, t + 2);
        PH_OPEN;
        __builtin_amdgcn_s_setprio(1);
        #pragma unroll
        for (int ii = 0; ii < 4; ++ii)
            #pragma unroll
            for (int j = 0; j < 4; ++j)
                acc[ii][j] = __builtin_amdgcn_mfma_f32_16x16x32_f16(fa[ii], bf[j], acc[ii][j], 0, 0, 0);
        __builtin_amdgcn_s_setprio(0);
        PH_CLOSE;
        // ---------- phase 1: B j=4..7 ----------
        #pragma unroll
        for (int j = 0; j < 4; ++j) bf[j] = *(const f16x8*)(sb + bro + (4 + j) * 1024);
        if (t + 1 < NKT) writeA(sCvt, (t + 1) & 1);   // regs issued 1 iter ago
        if (t + 2 < NKT) stageB(t + 2, bwS);
        PH_OPEN;
        __builtin_amdgcn_s_setprio(1);
        #pragma unroll
        for (int ii = 0; ii < 4; ++ii)
            #pragma unroll
            for (int j = 0; j < 4; ++j)
                acc[ii][4 + j] = __builtin_amdgcn_mfma_f32_16x16x32_f16(fa[ii], bf[j], acc[ii][4 + j], 0, 0, 0);
        __builtin_amdgcn_s_setprio(0);
        if (t < NKT - 2) { asm volatile("s_waitcnt vmcnt(8)" ::: "memory"); }
        else             { asm volatile("s_waitcnt vmcnt(0)" ::: "memory"); }
        PH_CLOSE;
        brS = (brS == 2) ? 0 : brS + 1;
        bwS = (bwS == 2) ? 0 : bwS + 1;
    };

    float4 sEven[4], sOdd[4];
    loadAreg(sEven, 0);
    writeA(sEven, 0);
    loadAreg(sOdd, 1);
    stageB(0, 0); stageB(1, 1);
    asm volatile("s_waitcnt lgkmcnt(0)" ::: "memory");
    asm volatile("s_waitcnt vmcnt(4)" ::: "memory");
    __builtin_amdgcn_s_barrier();
    __builtin_amdgcn_sched_barrier(0);

    #pragma unroll 1
    for (int tt = 0; tt < NKT; tt += 2) {
        body(tt,     sEven, sOdd);
        body(tt + 1, sOdd,  sEven);
    }

    // ---------------- epilogue ----------------
    const int colbase = ct * 256;

    float sd[8], vs[8];
    #pragma unroll
    for (int j = 0; j < 8; ++j) {
        const int col = colbase + wn * 128 + j * 16 + l15;
        sd[j] = sdec[b * 1024 + col];
        vs[j] = vw[col];
    }
    float psum[4][4] = {};
    #pragma unroll
    for (int i = 0; i < 4; ++i)
        #pragma unroll
        for (int j = 0; j < 8; ++j)
            #pragma unroll
            for (int q = 0; q < 4; ++q)
                psum[i][q] += tanh_mul(acc[i][j][q] + sd[j], vs[j]);

    #pragma unroll
    for (int i = 0; i < 4; ++i)
        #pragma unroll
        for (int q = 0; q < 4; ++q) {
            float s = psum[i][q];
            s += __shfl_xor(s, 1); s += __shfl_xor(s, 2);
            s += __shfl_xor(s, 4); s += __shfl_xor(s, 8);
            psum[i][q] = s;
        }

    __syncthreads();
    if (l15 == 0) {
        #pragma unroll
        for (int i = 0; i < 4; ++i)
            #pragma unroll
            for (int q = 0; q < 4; ++q)
                red[wn][wm * 64 + i * 16 + l4 * 4 + q] = psum[i][q];
    }
    __syncthreads();
    if (tid < 128)
        part[(size_t)ct * M_TOT + b * 2048 + rl * 128 + tid] =
            red[0][tid] + red[1][tid];
}

// softmax over L per batch; pos<0 -> -1e10; else sum NCT partials at compacted row.
__global__ __launch_bounds__(512) void softmax_kernel(
        const float* __restrict__ part, const int* __restrict__ pos,
        float* __restrict__ out) {
    int b = blockIdx.x;
    int tid = threadIdx.x;
    int lane = tid & 63, w = tid >> 6;
    __shared__ float sred[8];

    float vals[4];
    #pragma unroll
    for (int p = 0; p < 4; ++p) {
        int row = b * LSEQ + tid + p * 512;
        int pp = pos[row];
        float val = NEG_INF_F;
        if (pp >= 0) {
            int crow = b * 2048 + pp;
            val = 0.f;
            #pragma unroll
            for (int q = 0; q < NCT; ++q) val += part[(size_t)q * M_TOT + crow];
        }
        vals[p] = val;
    }
    float mx = fmaxf(fmaxf(vals[0], vals[1]), fmaxf(vals[2], vals[3]));
    #pragma unroll
    for (int m = 1; m < 64; m <<= 1) mx = fmaxf(mx, __shfl_xor(mx, m));
    if (lane == 0) sred[w] = mx;
    __syncthreads();
    float gmax = sred[0];
    #pragma unroll
    for (int i = 1; i < 8; ++i) gmax = fmaxf(gmax, sred[i]);

    float es[4]; float ssum = 0.f;
    #pragma unroll
    for (int p = 0; p < 4; ++p) { es[p] = expf(vals[p] - gmax); ssum += es[p]; }
    #pragma unroll
    for (int m = 1; m < 64; m <<= 1) ssum += __shfl_xor(ssum, m);
    __syncthreads();
    if (lane == 0) sred[w] = ssum;
    __syncthreads();
    float gsum = 0.f;
    #pragma unroll
    for (int i = 0; i < 8; ++i) gsum += sred[i];
    float inv = 1.f / gsum;
    #pragma unroll
    for (int p = 0; p < 4; ++p)
        out[b * LSEQ + tid + p * 512] = es[p] * inv;
}

extern "C" void kernel_launch(void* const* d_in, const int* in_sizes, int n_in,
                              void* d_out, int out_size, void* d_ws, size_t ws_size,
                              hipStream_t stream) {
    const float* enc    = (const float*)d_in[0];
    const int*   mask   = (const int*)  d_in[1];
    const float* v      = (const float*)d_in[2];
    const float* attn_w = (const float*)d_in[3];
    const float* attn_b = (const float*)d_in[4];
    const float* v_w    = (const float*)d_in[5];
    float* out = (float*)d_out;

    char* ws = (char*)d_ws;
    float* sdec  = (float*)(ws + WS_SDEC_OFF);
    float* part  = (float*)(ws + WS_PART_OFF);
    int*   pos   = (int*)  (ws + WS_POS_OFF);
    int*   ridx  = (int*)  (ws + WS_RIDX_OFF);
    int*   nkeep = (int*)  (ws + WS_NKEEP_OFF);
    f16*   weT   = (f16*)  (ws + WS_WET_OFF);

    hipLaunchKernelGGL(prep_kernel,    dim3(528),  dim3(256), 0, stream,
                       attn_w, weT, v, attn_b, sdec, mask, ridx, pos, nkeep);
    hipLaunchKernelGGL(fused_gemm,     dim3(1024), dim3(256), 0, stream,
                       enc, weT, sdec, v_w, ridx, nkeep, part);
    hipLaunchKernelGGL(softmax_kernel, dim3(16),   dim3(512), 0, stream, part, pos, out);
}